// Round 8
// baseline (218.129 us; speedup 1.0000x reference)
//
#include <hip/hip_runtime.h>
#include <cstddef>

namespace {

constexpr int B = 4, V = 20000, P = 400000, NN = 50000, MP = 32;
constexpr float GAMMA = 10.0f, INV_GAMMA = 0.1f;
constexpr float KSOFT = 2.0f;
constexpr float THRESH = 1.0f;
constexpr float W_WL = 1.0f, W_CONG = 0.5f;
constexpr int BPB = 192;                   // phase-B blocks per batch (768 = 3/CU at 42KB LDS)
constexpr int NET_GRID = BPB * B;          // 768 blocks, 4 waves
constexpr int GRPS = 5;                    // 80 contiguous nets per wave-stream
constexpr int NPW = GRPS * 16;             // 80  (625*80 = 50000 exactly)
constexpr int A_SUBS = 196;                // phase A: 196*256 = 50176 >= NN
constexpr int A_GRID = A_SUBS * B;
constexpr int PREP_N = NN * MP;            // 1.6M, largest fused-prep range

typedef __attribute__((ext_vector_type(8)))  short bf16x8;
typedef __attribute__((ext_vector_type(16))) float f32x16;

__device__ __forceinline__ float fast_rcp(float x) { return __builtin_amdgcn_rcpf(x); }
__device__ __forceinline__ short f2bf(float f) {
    unsigned u = __float_as_uint(f);
    u += 0x7fffu + ((u >> 16) & 1u);
    return (short)(u >> 16);
}
template <int CTRL>
__device__ __forceinline__ float dpp_mov(float x, float id) {
    return __int_as_float(__builtin_amdgcn_update_dpp(
        __float_as_int(id), __float_as_int(x), CTRL, 0xf, 0xf, false));
}
__device__ __forceinline__ float rdlane(float x, int l) {
    return __int_as_float(__builtin_amdgcn_readlane(__float_as_int(x), l));
}
#define DPP5(x, OP, ID)                              \
    x = OP(x, dpp_mov<0x111>(x, ID));                \
    x = OP(x, dpp_mov<0x112>(x, ID));                \
    x = OP(x, dpp_mov<0x114>(x, ID));                \
    x = OP(x, dpp_mov<0x118>(x, ID));                \
    x = OP(x, dpp_mov<0x142>(x, ID));
__device__ __forceinline__ float op_add(float a, float b) { return a + b; }

// Fused prep (R6-exact): zero accumulators + macro_prep + n2p transpose.
__global__ void __launch_bounds__(256)
prep_kernel(const float* __restrict__ positions,
            const float* __restrict__ rot_onehot,
            float4* __restrict__ mac,
            const int* __restrict__ n2p,
            int* __restrict__ n2pT,
            float* __restrict__ zacc) {    // hpwl[B] + pen[B]
    int i = blockIdx.x * blockDim.x + threadIdx.x;
    if (i < 2 * B) zacc[i] = 0.0f;
    if (i < B * V) {
        float2 pos = ((const float2*)positions)[i];
        float4 w = ((const float4*)rot_onehot)[i];
        mac[i] = make_float4(pos.x, pos.y, w.x - w.z, w.y - w.w);
    }
    if (i < PREP_N) {
        int n = i >> 5, j = i & 31;
        n2pT[j * NN + n] = n2p[i];
    }
}

// pin_pos (R6-exact): 2 pins per thread.
__global__ void __launch_bounds__(256)
pin_pos_kernel(const float4* __restrict__ mac,
               const int* __restrict__ pin_to_macro,
               const float* __restrict__ pin_offsets,
               float* __restrict__ pin_pos) {
    int idx = blockIdx.x * blockDim.x + threadIdx.x;
    if (idx >= B * P / 2) return;
    int b = idx / (P / 2);
    int t = idx - b * (P / 2);                 // pin-pair index
    int2 m2 = ((const int2*)pin_to_macro)[t];
    float4 o2 = ((const float4*)pin_offsets)[t];
    float4 md0 = mac[(size_t)b * V + m2.x];
    float4 md1 = mac[(size_t)b * V + m2.y];
    float4 r;
    r.x = md0.x + md0.z * o2.x - md0.w * o2.y;
    r.y = md0.y + md0.w * o2.x + md0.z * o2.y;
    r.z = md1.x + md1.z * o2.z - md1.w * o2.w;
    r.w = md1.y + md1.w * o2.z + md1.z * o2.w;
    ((float4*)pin_pos)[idx] = r;               // out index b*P/2 + t == idx
}

// Phase A (R6-exact): one net per LANE; full gather preload; emits per-net
// factor records (4 exp per NET, hidden under gather latency).
__global__ void __launch_bounds__(256)
bbox_kernel(const float* __restrict__ pin_pos,
            const int* __restrict__ n2pT,
            const float* __restrict__ net_weights,
            float4* __restrict__ fac,      // B*NN*2 float4 records
            float* __restrict__ hpwl) {
    __shared__ float hps[4];
    int blk = blockIdx.x;
    int xcd = blk & 7;
    int b = xcd >> 1;
    int sub = ((blk >> 3) << 1) | (xcd & 1);
    int tid = threadIdx.x;
    int wave = tid >> 6;
    int lane = tid & 63;

    int n = sub * 256 + wave * 64 + lane;
    bool inrange = n < NN;
    int nc = inrange ? n : (NN - 1);

    const float2* pp = (const float2*)(pin_pos + (size_t)b * P * 2);

    int pi[MP];
    #pragma unroll
    for (int j = 0; j < MP; ++j) pi[j] = n2pT[j * NN + nc];

    float2 q[MP];
    #pragma unroll
    for (int j = 0; j < MP; ++j) q[j] = pp[pi[j] >= 0 ? pi[j] : 0];

    float ex1 = 0.f, ex2 = 0.f, ey1 = 0.f, ey2 = 0.f;
    float vxmax = -1e30f, vxmin = 1e30f, vymax = -1e30f, vymin = 1e30f;
    #pragma unroll
    for (int j = 0; j < MP; ++j) {
        bool v = pi[j] >= 0;
        float e1x = __expf(GAMMA * q[j].x);
        float e1y = __expf(GAMMA * q[j].y);
        ex1 += v ? e1x : 0.f;
        ex2 += v ? fast_rcp(e1x) : 0.f;
        ey1 += v ? e1y : 0.f;
        ey2 += v ? fast_rcp(e1y) : 0.f;
        vxmax = fmaxf(vxmax, v ? q[j].x : -1e30f);
        vxmin = fminf(vxmin, v ? q[j].x :  1e30f);
        vymax = fmaxf(vymax, v ? q[j].y : -1e30f);
        vymin = fminf(vymin, v ? q[j].y :  1e30f);
    }
    float w = net_weights[nc];
    float wl = __logf(ex1 * ex2 * ey1 * ey2) * INV_GAMMA;
    float hp = inrange ? wl * w : 0.f;

    if (inrange) {
        float xmin = (vxmin + 1.0f) * 31.5f;
        float xmax = (vxmax + 1.0f) * 31.5f;
        float ymin = (vymin + 1.0f) * 31.5f;
        float ymax = (vymax + 1.0f) * 31.5f;
        float sz = fmaxf((xmax - xmin + 1.0f) * (ymax - ymin + 1.0f), 1.0f);
        float ux = __expf(fmaf( KSOFT, xmin, -32.5f * KSOFT));
        float wx = __expf(fmaf(-KSOFT, xmax,  31.5f * KSOFT));
        float uy = __expf(fmaf( KSOFT, ymin, -32.5f * KSOFT));
        float wy = __expf(fmaf(-KSOFT, ymax,  31.5f * KSOFT));
        float cx = fmaf(ux, wx, 1.0f);
        float cy = fmaf(uy, wy, 1.0f) * sz;    // 1/sz folded into A-side
        float4* fp = fac + ((size_t)b * NN + n) * 2;
        fp[0] = make_float4(ux, wx, cx, 0.f);
        fp[1] = make_float4(uy * sz, wy * sz, cy, 0.f);
    }
    DPP5(hp, op_add, 0.0f);
    float tot = rdlane(hp, 31) + rdlane(hp, 63);
    if (lane == 0) hps[wave] = tot;
    __syncthreads();
    if (tid == 0) atomicAdd(&hpwl[b], hps[0] + hps[1] + hps[2] + hps[3]);
}

// Phase B, R8: R6's proven loop structure (LDS-stage up front, register
// prefetch one group ahead, exp-free inner math) UNCHANGED; only the
// epilogue/grid change for occupancy:
//  * waves PAIR-share two 16KB tiles via LDS atomicAdd (each cell = exactly
//    2 commutative f32 adds onto 0.0 -> bit-deterministic; slab value keeps
//    R6's (w0+w1)+(w2+w3) grouping).
//  * stage lives in its own 10KB region (must outlive the loop now).
//  * LDS 64KB -> 42KB => 3 blocks/CU; BPB 128->192 (768 blocks = 3/CU, all
//    co-resident) => 3 waves/SIMD (was 2) on a latency-bound kernel.
//  * NPW 112->80, GRPS 7->5 (compile-time unroll preserved); 625 streams
//    cover NN exactly; idle streams skip compute, join barriers.
__global__ void __launch_bounds__(256)
rudy_kernel(const float4* __restrict__ fac,
            float* __restrict__ slabs) {   // NET_GRID * 4096 (aliases pin_pos)
    __shared__ float tiles[2][4096];           // pair-shared output tiles (32KB)
    __shared__ float stage[4][640];            // per-wave 80-net factor stage (10KB)
    int x = blockIdx.x;
    int xcd = x & 7;
    int b = xcd >> 1;
    int sub = ((x >> 3) << 1) | (xcd & 1);     // 0..BPB-1
    int tid = threadIdx.x;
    int wave = tid >> 6;
    int lane = tid & 63;

    int s = sub * 4 + wave;                    // wave-stream id, 0..767
    int s0 = s * NPW;                          // first net of this stream
    const float* ff = (const float*)(fac + (size_t)b * NN * 2);  // dword view

    // ---- stage: 80 nets * 8 dwords = 640 dwords, 10 per lane, coalesced ----
    #pragma unroll
    for (int k = 0; k < 10; ++k) {
        int d = s0 * 8 + k * 64 + lane;        // dword index into batch fac
        stage[wave][k * 64 + lane] = ff[d < NN * 8 ? d : 0];
    }
    const float4* st = (const float4*)stage[wave];

    f32x16 acc00, acc01, acc10, acc11;
    #pragma unroll
    for (int r = 0; r < 16; ++r) { acc00[r] = 0.f; acc01[r] = 0.f; acc10[r] = 0.f; acc11[r] = 0.f; }

    int half8 = (lane >> 5) * 8;               // k-slot base for this half-wave
    float g2 = (float)(lane & 31);             // row/col 0..31 (g2+32 via EnH/EpH)

    float En0 = __expf(fmaf(-KSOFT, g2,  32.0f * KSOFT));
    float Ep0 = __expf(fmaf( KSOFT, g2, -32.0f * KSOFT));
    float EnH = __expf(-KSOFT * g2);
    float EpH = __expf( KSOFT * g2);

    if (s0 < NN) {                             // idle tail streams skip compute
        float4 fbc[8], fyc[8];
        #pragma unroll
        for (int j = 0; j < 8; ++j) {
            fbc[j] = st[2 * (half8 + j)];
            fyc[j] = st[2 * (half8 + j) + 1];
        }
        #pragma unroll
        for (int grp = 0; grp < GRPS; ++grp) {
            float4 fbn[8], fyn[8];
            if (grp + 1 < GRPS) {              // prefetch next group's LDS reads
                #pragma unroll
                for (int j = 0; j < 8; ++j) {
                    fbn[j] = st[2 * ((grp + 1) * 16 + half8 + j)];
                    fyn[j] = st[2 * ((grp + 1) * 16 + half8 + j) + 1];
                }
            }
            int nb = s0 + grp * 16 + half8;
            bf16x8 A0, A1, B0, B1;
            #pragma unroll
            for (int j = 0; j < 8; ++j) {
                float4 fb = fbc[j];
                float4 fy = fyc[j];
                float okf = (nb + j < NN) ? 1.0f : 0.0f;
                float b0 = fast_rcp(fmaf(En0, fb.x, fmaf(Ep0, fb.y, fb.z)));
                float b1 = fast_rcp(fmaf(EnH, fb.x, fmaf(EpH, fb.y, fb.z)));
                float a0 = fast_rcp(fmaf(En0, fy.x, fmaf(Ep0, fy.y, fy.z))) * okf;
                float a1 = fast_rcp(fmaf(EnH, fy.x, fmaf(EpH, fy.y, fy.z))) * okf;
                A0[j] = f2bf(a0); A1[j] = f2bf(a1);
                B0[j] = f2bf(b0); B1[j] = f2bf(b1);
            }
            acc00 = __builtin_amdgcn_mfma_f32_32x32x16_bf16(A0, B0, acc00, 0, 0, 0);
            acc01 = __builtin_amdgcn_mfma_f32_32x32x16_bf16(A0, B1, acc01, 0, 0, 0);
            acc10 = __builtin_amdgcn_mfma_f32_32x32x16_bf16(A1, B0, acc10, 0, 0, 0);
            acc11 = __builtin_amdgcn_mfma_f32_32x32x16_bf16(A1, B1, acc11, 0, 0, 0);
            if (grp + 1 < GRPS) {
                #pragma unroll
                for (int j = 0; j < 8; ++j) { fbc[j] = fbn[j]; fyc[j] = fyn[j]; }
            }
        }
    }

    // ---- epilogue: zero pair tiles -> barrier -> 2-way ds_add -> barrier ----
    for (int k = tid; k < 8192; k += 256) ((float*)tiles)[k] = 0.0f;
    __syncthreads();
    // C/D layout: col=lane&31, row=(r&3)+8*(r>>2)+4*(lane>>5)
    int col = lane & 31, rq = lane >> 5;
    float* wt = tiles[wave >> 1];
    #pragma unroll
    for (int r = 0; r < 16; ++r) {
        int row = (r & 3) + 8 * (r >> 2) + 4 * rq;
        atomicAdd(&wt[row * 64 + col],             acc00[r]);
        atomicAdd(&wt[row * 64 + col + 32],        acc01[r]);
        atomicAdd(&wt[(row + 32) * 64 + col],      acc10[r]);
        atomicAdd(&wt[(row + 32) * 64 + col + 32], acc11[r]);
    }
    __syncthreads();
    float* slab = slabs + ((size_t)b * BPB + sub) * 4096;
    for (int k = tid; k < 4096; k += 256)
        slab[k] = tiles[0][k] + tiles[1][k];
}

// Sum BPB slabs -> rudy (R6-exact, BPB=192 now). XCD-pinned to writers' L2.
__global__ void __launch_bounds__(256)
rudy_reduce_kernel(const float* __restrict__ slabs, float* __restrict__ rudy) {
    int blk = blockIdx.x;                       // 64
    int xcd = blk & 7;
    int b = xcd >> 1;
    int sub = ((blk >> 3) << 1) | (xcd & 1);    // 0..15
    int c = sub * 256 + threadIdx.x;            // cell 0..4095
    const float* base = slabs + (size_t)b * BPB * 4096 + c;
    float a0 = 0.f, a1 = 0.f, a2 = 0.f, a3 = 0.f;
    #pragma unroll 4
    for (int s = 0; s < BPB; s += 4) {          // BPB=192, %4==0
        a0 += base[(size_t)(s + 0) * 4096];
        a1 += base[(size_t)(s + 1) * 4096];
        a2 += base[(size_t)(s + 2) * 4096];
        a3 += base[(size_t)(s + 3) * 4096];
    }
    rudy[b * 4096 + c] = (a0 + a1) + (a2 + a3);
}

__global__ void conv_penalty_kernel(const float* __restrict__ rudy,
                                    float* __restrict__ pen) {
    int blk = blockIdx.x;
    int b = blk >> 4, chunk = blk & 15;
    int r0 = chunk * 4;
    __shared__ float t2[10][64];
    int tid = threadIdx.x;
    for (int k = tid; k < 640; k += 256) {
        int r = k >> 6, c = k & 63, row = r0 - 3 + r;
        t2[r][c] = (row >= 0 && row < 64) ? rudy[b * 4096 + row * 64 + c] : 0.f;
    }
    __syncthreads();
    float g1[7];
    #pragma unroll
    for (int i = 0; i < 7; ++i) { float t = (float)(i - 3); g1[i] = __expf(-t * t / 4.5f); }
    float s1 = g1[0] + g1[1] + g1[2] + g1[3] + g1[4] + g1[5] + g1[6];
    float inv = fast_rcp(s1 * s1);
    int i = tid >> 6, j = tid & 63;
    float acc = 0.f;
    #pragma unroll
    for (int di = -3; di <= 3; ++di) {
        #pragma unroll
        for (int dj = -3; dj <= 3; ++dj) {
            int jj = j + dj;
            float val = (jj >= 0 && jj < 64) ? t2[i + 3 + di][jj] : 0.f;
            acc += g1[di + 3] * g1[dj + 3] * val;
        }
    }
    acc *= inv;
    float ov = acc - THRESH;
    float p = ov > 0.f ? ov * ov : 0.f;
    DPP5(p, op_add, 0.0f);
    float tot = rdlane(p, 31) + rdlane(p, 63);
    if ((tid & 63) == 0) atomicAdd(&pen[b], tot);
}

__global__ void finalize_kernel(const float* __restrict__ hpwl,
                                const float* __restrict__ pen,
                                float* __restrict__ out) {
    int i = threadIdx.x;
    if (i < B) out[i] = W_WL * hpwl[i] + W_CONG * pen[i];
}

} // namespace

extern "C" void kernel_launch(void* const* d_in, const int* in_sizes, int n_in,
                              void* d_out, int out_size, void* d_ws, size_t ws_size,
                              hipStream_t stream) {
    const float* positions    = (const float*)d_in[0];
    const int*   net_to_pin   = (const int*)d_in[1];
    const int*   pin_to_macro = (const int*)d_in[2];
    const float* pin_offsets  = (const float*)d_in[3];
    const float* rot_onehot   = (const float*)d_in[4];
    const float* net_weights  = (const float*)d_in[5];
    float* out = (float*)d_out;

    // ws: pin_pos | rudy | hpwl | pen | mac | fac | n2pT   (~28 MB)
    // slabs (768*16KB = 12.58 MB) ALIASES pin_pos (12.8 MB): pin_pos is dead
    // after bbox_kernel, and rudy_kernel runs strictly after it on the stream.
    float*  pin_pos = (float*)d_ws;
    float*  rudy    = pin_pos + (size_t)B * P * 2;
    float*  hpwl    = rudy + (size_t)B * 64 * 64;
    float*  pen     = hpwl + B;
    float4* mac     = (float4*)(pen + B);
    float4* fac     = mac + (size_t)B * V;             // B*NN*2 float4
    int*    n2pT    = (int*)(fac + (size_t)B * NN * 2);
    float*  slabs   = pin_pos;                 // reuse (see comment above)

    prep_kernel<<<(PREP_N + 255) / 256, 256, 0, stream>>>(
        positions, rot_onehot, mac, net_to_pin, n2pT, hpwl);
    pin_pos_kernel<<<(B * P / 2 + 255) / 256, 256, 0, stream>>>(
        mac, pin_to_macro, pin_offsets, pin_pos);
    bbox_kernel<<<A_GRID, 256, 0, stream>>>(pin_pos, n2pT, net_weights, fac, hpwl);
    rudy_kernel<<<NET_GRID, 256, 0, stream>>>(fac, slabs);
    rudy_reduce_kernel<<<64, 256, 0, stream>>>(slabs, rudy);
    conv_penalty_kernel<<<64, 256, 0, stream>>>(rudy, pen);
    finalize_kernel<<<1, 64, 0, stream>>>(hpwl, pen, out);
}

// Round 10
// 151.050 us; speedup vs baseline: 1.4441x; 1.4441x over previous
//
#include <hip/hip_runtime.h>
#include <cstddef>

namespace {

constexpr int B = 4, V = 20000, P = 400000, NN = 50000, MP = 32;
constexpr float GAMMA = 10.0f, INV_GAMMA = 0.1f;
constexpr float KSOFT = 2.0f;
constexpr float THRESH = 1.0f;
constexpr float W_WL = 1.0f, W_CONG = 0.5f;
constexpr int BPB = 128;                   // phase-B blocks per batch (512 blocks = 2/CU)
constexpr int NET_GRID = BPB * B;          // 512 blocks, 4 waves
constexpr int GRPS = 7;                    // 112 contiguous nets per wave-stream
constexpr int NPW = GRPS * 16;             // 112
constexpr int A_SUBS = 196;                // phase A: 196*256 = 50176 >= NN
constexpr int A_GRID = A_SUBS * B;
constexpr int PREP_N = NN * MP;            // 1.6M, largest fused-prep range

typedef __attribute__((ext_vector_type(8)))  short bf16x8;
typedef __attribute__((ext_vector_type(16))) float f32x16;

__device__ __forceinline__ float fast_rcp(float x) { return __builtin_amdgcn_rcpf(x); }
__device__ __forceinline__ short f2bf(float f) {
    unsigned u = __float_as_uint(f);
    u += 0x7fffu + ((u >> 16) & 1u);
    return (short)(u >> 16);
}
template <int CTRL>
__device__ __forceinline__ float dpp_mov(float x, float id) {
    return __int_as_float(__builtin_amdgcn_update_dpp(
        __float_as_int(id), __float_as_int(x), CTRL, 0xf, 0xf, false));
}
__device__ __forceinline__ float rdlane(float x, int l) {
    return __int_as_float(__builtin_amdgcn_readlane(__float_as_int(x), l));
}
#define DPP5(x, OP, ID)                              \
    x = OP(x, dpp_mov<0x111>(x, ID));                \
    x = OP(x, dpp_mov<0x112>(x, ID));                \
    x = OP(x, dpp_mov<0x114>(x, ID));                \
    x = OP(x, dpp_mov<0x118>(x, ID));                \
    x = OP(x, dpp_mov<0x142>(x, ID));
__device__ __forceinline__ float op_add(float a, float b) { return a + b; }

// Fused prep: zero accumulators + macro_prep + n2p transpose in ONE launch.
__global__ void __launch_bounds__(256)
prep_kernel(const float* __restrict__ positions,
            const float* __restrict__ rot_onehot,
            float4* __restrict__ mac,
            const int* __restrict__ n2p,
            int* __restrict__ n2pT,
            float* __restrict__ zacc) {    // hpwl[B] + pen[B]
    int i = blockIdx.x * blockDim.x + threadIdx.x;
    if (i < 2 * B) zacc[i] = 0.0f;
    if (i < B * V) {
        float2 pos = ((const float2*)positions)[i];
        float4 w = ((const float4*)rot_onehot)[i];
        mac[i] = make_float4(pos.x, pos.y, w.x - w.z, w.y - w.w);
    }
    if (i < PREP_N) {
        int n = i >> 5, j = i & 31;
        n2pT[j * NN + n] = n2p[i];
    }
}

// pin_pos: 2 pins per thread (int2 / float4 loads, float4 store).
__global__ void __launch_bounds__(256)
pin_pos_kernel(const float4* __restrict__ mac,
               const int* __restrict__ pin_to_macro,
               const float* __restrict__ pin_offsets,
               float* __restrict__ pin_pos) {
    int idx = blockIdx.x * blockDim.x + threadIdx.x;
    if (idx >= B * P / 2) return;
    int b = idx / (P / 2);
    int t = idx - b * (P / 2);                 // pin-pair index
    int2 m2 = ((const int2*)pin_to_macro)[t];
    float4 o2 = ((const float4*)pin_offsets)[t];
    float4 md0 = mac[(size_t)b * V + m2.x];
    float4 md1 = mac[(size_t)b * V + m2.y];
    float4 r;
    r.x = md0.x + md0.z * o2.x - md0.w * o2.y;
    r.y = md0.y + md0.w * o2.x + md0.z * o2.y;
    r.z = md1.x + md1.z * o2.z - md1.w * o2.w;
    r.w = md1.y + md1.w * o2.z + md1.z * o2.w;
    ((float4*)pin_pos)[idx] = r;               // out index b*P/2 + t == idx
}

// Phase A: one net per LANE; full gather preload (R4-proven).  Also emits
// the per-net FACTOR RECORD for rudy (ux,wx,cx | uy*sz,wy*sz,cy*sz) — 4 exp
// per NET total (vs per lane*net in rudy), hidden under this kernel's gather
// latency.  bbox itself is no longer materialized.
__global__ void __launch_bounds__(256)
bbox_kernel(const float* __restrict__ pin_pos,
            const int* __restrict__ n2pT,
            const float* __restrict__ net_weights,
            float4* __restrict__ fac,      // B*NN*2 float4 records
            float* __restrict__ hpwl) {
    __shared__ float hps[4];
    int blk = blockIdx.x;
    int xcd = blk & 7;
    int b = xcd >> 1;
    int sub = ((blk >> 3) << 1) | (xcd & 1);
    int tid = threadIdx.x;
    int wave = tid >> 6;
    int lane = tid & 63;

    int n = sub * 256 + wave * 64 + lane;
    bool inrange = n < NN;
    int nc = inrange ? n : (NN - 1);

    const float2* pp = (const float2*)(pin_pos + (size_t)b * P * 2);

    int pi[MP];
    #pragma unroll
    for (int j = 0; j < MP; ++j) pi[j] = n2pT[j * NN + nc];

    float2 q[MP];
    #pragma unroll
    for (int j = 0; j < MP; ++j) q[j] = pp[pi[j] >= 0 ? pi[j] : 0];

    float ex1 = 0.f, ex2 = 0.f, ey1 = 0.f, ey2 = 0.f;
    float vxmax = -1e30f, vxmin = 1e30f, vymax = -1e30f, vymin = 1e30f;
    #pragma unroll
    for (int j = 0; j < MP; ++j) {
        bool v = pi[j] >= 0;
        float e1x = __expf(GAMMA * q[j].x);
        float e1y = __expf(GAMMA * q[j].y);
        ex1 += v ? e1x : 0.f;
        ex2 += v ? fast_rcp(e1x) : 0.f;
        ey1 += v ? e1y : 0.f;
        ey2 += v ? fast_rcp(e1y) : 0.f;
        vxmax = fmaxf(vxmax, v ? q[j].x : -1e30f);
        vxmin = fminf(vxmin, v ? q[j].x :  1e30f);
        vymax = fmaxf(vymax, v ? q[j].y : -1e30f);
        vymin = fminf(vymin, v ? q[j].y :  1e30f);
    }
    float w = net_weights[nc];
    float wl = __logf(ex1 * ex2 * ey1 * ey2) * INV_GAMMA;
    float hp = inrange ? wl * w : 0.f;

    if (inrange) {
        float xmin = (vxmin + 1.0f) * 31.5f;
        float xmax = (vxmax + 1.0f) * 31.5f;
        float ymin = (vymin + 1.0f) * 31.5f;
        float ymax = (vymax + 1.0f) * 31.5f;
        float sz = fmaxf((xmax - xmin + 1.0f) * (ymax - ymin + 1.0f), 1.0f);
        // factored sigmoid-pair factors (R2-validated math):
        //   sig(a)*sig(b) = rcp(En(g)*u + Ep(g)*w + c), c = 1 + u*w
        float ux = __expf(fmaf( KSOFT, xmin, -32.5f * KSOFT));
        float wx = __expf(fmaf(-KSOFT, xmax,  31.5f * KSOFT));
        float uy = __expf(fmaf( KSOFT, ymin, -32.5f * KSOFT));
        float wy = __expf(fmaf(-KSOFT, ymax,  31.5f * KSOFT));
        float cx = fmaf(ux, wx, 1.0f);
        float cy = fmaf(uy, wy, 1.0f) * sz;    // 1/sz folded into A-side
        float4* fp = fac + ((size_t)b * NN + n) * 2;
        fp[0] = make_float4(ux, wx, cx, 0.f);
        fp[1] = make_float4(uy * sz, wy * sz, cy, 0.f);
    }
    DPP5(hp, op_add, 0.0f);
    float tot = rdlane(hp, 31) + rdlane(hp, 63);
    if (lane == 0) hps[wave] = tot;
    __syncthreads();
    if (tid == 0) atomicAdd(&hpwl[b], hps[0] + hps[1] + hps[2] + hps[3]);
}

// Phase B (R3/R4 latency structure EXACTLY preserved — LDS-stage up front,
// register prefetch one group ahead, pure-register compute, private per-wave
// tile, no atomics, one barrier).  Stages the precomputed 8-float factor
// records (14 dwords/lane), so the j-loop has ZERO exp: 8 fma + 4 rcp + 2 mul
// + 4 cvt per net.  DO NOT restructure: the stage-in-tile-head + private-tile
// shape is what keeps the 32-float4 double-buffer in registers (R5/R8: any
// deviation demotes it to serial ds_reads, 4x slower).
__global__ void __launch_bounds__(256)
rudy_kernel(const float4* __restrict__ fac,
            float* __restrict__ slabs) {   // NET_GRID * 4096 (aliases pin_pos)
    __shared__ float lds4[4][4096];            // per-wave tile; head doubles as stage
    int x = blockIdx.x;
    int xcd = x & 7;
    int b = xcd >> 1;
    int sub = ((x >> 3) << 1) | (xcd & 1);     // 0..BPB-1
    int tid = threadIdx.x;
    int wave = tid >> 6;
    int lane = tid & 63;

    int s = sub * 4 + wave;                    // wave-stream id, 0..511
    int s0 = s * NPW;                          // first net of this stream
    const float* ff = (const float*)(fac + (size_t)b * NN * 2);  // dword view

    // ---- stage: 112 nets * 8 dwords = 896 dwords, 14 per lane, coalesced ----
    #pragma unroll
    for (int k = 0; k < 14; ++k) {
        int d = s0 * 8 + k * 64 + lane;        // dword index into batch fac
        lds4[wave][k * 64 + lane] = ff[d < NN * 8 ? d : 0];
    }
    const float4* st = (const float4*)lds4[wave];

    f32x16 acc00, acc01, acc10, acc11;
    #pragma unroll
    for (int r = 0; r < 16; ++r) { acc00[r] = 0.f; acc01[r] = 0.f; acc10[r] = 0.f; acc11[r] = 0.f; }

    int half8 = (lane >> 5) * 8;               // k-slot base for this half-wave
    float g2 = (float)(lane & 31);             // row/col 0..31 (g2+32 via EnH/EpH)

    // per-lane exp constants: En(g)=e^{-k(g-32)}, Ep(g)=e^{k(g-32)}; for g+32
    // the shift cancels: EnH=e^{-k*g2}, EpH=e^{k*g2}.
    float En0 = __expf(fmaf(-KSOFT, g2,  32.0f * KSOFT));
    float Ep0 = __expf(fmaf( KSOFT, g2, -32.0f * KSOFT));
    float EnH = __expf(-KSOFT * g2);
    float EpH = __expf( KSOFT * g2);

    if (s0 < NN) {                             // idle tail streams exit fast
        float4 fbc[8], fyc[8];
        #pragma unroll
        for (int j = 0; j < 8; ++j) {
            fbc[j] = st[2 * (half8 + j)];
            fyc[j] = st[2 * (half8 + j) + 1];
        }
        #pragma unroll
        for (int grp = 0; grp < GRPS; ++grp) {
            float4 fbn[8], fyn[8];
            if (grp + 1 < GRPS) {              // prefetch next group's LDS reads
                #pragma unroll
                for (int j = 0; j < 8; ++j) {
                    fbn[j] = st[2 * ((grp + 1) * 16 + half8 + j)];
                    fyn[j] = st[2 * ((grp + 1) * 16 + half8 + j) + 1];
                }
            }
            int nb = s0 + grp * 16 + half8;
            bf16x8 A0, A1, B0, B1;
            #pragma unroll
            for (int j = 0; j < 8; ++j) {
                float4 fb = fbc[j];
                float4 fy = fyc[j];
                float okf = (nb + j < NN) ? 1.0f : 0.0f;
                // x-profile (B = X): cols g2 / g2+32
                float b0 = fast_rcp(fmaf(En0, fb.x, fmaf(Ep0, fb.y, fb.z)));
                float b1 = fast_rcp(fmaf(EnH, fb.x, fmaf(EpH, fb.y, fb.z)));
                // y-profile (A = Y^T, 1/sz folded): rows g2 / g2+32
                float a0 = fast_rcp(fmaf(En0, fy.x, fmaf(Ep0, fy.y, fy.z))) * okf;
                float a1 = fast_rcp(fmaf(EnH, fy.x, fmaf(EpH, fy.y, fy.z))) * okf;
                A0[j] = f2bf(a0); A1[j] = f2bf(a1);
                B0[j] = f2bf(b0); B1[j] = f2bf(b1);
            }
            acc00 = __builtin_amdgcn_mfma_f32_32x32x16_bf16(A0, B0, acc00, 0, 0, 0);
            acc01 = __builtin_amdgcn_mfma_f32_32x32x16_bf16(A0, B1, acc01, 0, 0, 0);
            acc10 = __builtin_amdgcn_mfma_f32_32x32x16_bf16(A1, B0, acc10, 0, 0, 0);
            acc11 = __builtin_amdgcn_mfma_f32_32x32x16_bf16(A1, B1, acc11, 0, 0, 0);
            if (grp + 1 < GRPS) {
                #pragma unroll
                for (int j = 0; j < 8; ++j) { fbc[j] = fbn[j]; fyc[j] = fyn[j]; }
            }
        }
    }

    // ---- plain-store own tile (each (lane,r) owns a unique cell; no init,
    //      no atomics; overwrites the dead stage region) ----
    // C/D layout: col=lane&31, row=(r&3)+8*(r>>2)+4*(lane>>5)
    int col = lane & 31, rq = lane >> 5;
    float* wt = lds4[wave];
    #pragma unroll
    for (int r = 0; r < 16; ++r) {
        int row = (r & 3) + 8 * (r >> 2) + 4 * rq;
        wt[row * 64 + col]             = acc00[r];
        wt[row * 64 + col + 32]        = acc01[r];
        wt[(row + 32) * 64 + col]      = acc10[r];
        wt[(row + 32) * 64 + col + 32] = acc11[r];
    }
    __syncthreads();
    float* slab = slabs + ((size_t)b * BPB + sub) * 4096;
    for (int k = tid; k < 4096; k += 256)
        slab[k] = (lds4[0][k] + lds4[1][k]) + (lds4[2][k] + lds4[3][k]);
}

// Sum BPB slabs -> rudy. XCD-pinned to the pair that wrote the slabs (L2 hits).
__global__ void __launch_bounds__(256)
rudy_reduce_kernel(const float* __restrict__ slabs, float* __restrict__ rudy) {
    int blk = blockIdx.x;                       // 64
    int xcd = blk & 7;
    int b = xcd >> 1;
    int sub = ((blk >> 3) << 1) | (xcd & 1);    // 0..15
    int c = sub * 256 + threadIdx.x;            // cell 0..4095
    const float* base = slabs + (size_t)b * BPB * 4096 + c;
    float a0 = 0.f, a1 = 0.f, a2 = 0.f, a3 = 0.f;
    #pragma unroll 4
    for (int s = 0; s < BPB; s += 4) {
        a0 += base[(size_t)(s + 0) * 4096];
        a1 += base[(size_t)(s + 1) * 4096];
        a2 += base[(size_t)(s + 2) * 4096];
        a3 += base[(size_t)(s + 3) * 4096];
    }
    rudy[b * 4096 + c] = (a0 + a1) + (a2 + a3);
}

__global__ void conv_penalty_kernel(const float* __restrict__ rudy,
                                    float* __restrict__ pen) {
    int blk = blockIdx.x;
    int b = blk >> 4, chunk = blk & 15;
    int r0 = chunk * 4;
    __shared__ float t2[10][64];
    int tid = threadIdx.x;
    for (int k = tid; k < 640; k += 256) {
        int r = k >> 6, c = k & 63, row = r0 - 3 + r;
        t2[r][c] = (row >= 0 && row < 64) ? rudy[b * 4096 + row * 64 + c] : 0.f;
    }
    __syncthreads();
    float g1[7];
    #pragma unroll
    for (int i = 0; i < 7; ++i) { float t = (float)(i - 3); g1[i] = __expf(-t * t / 4.5f); }
    float s1 = g1[0] + g1[1] + g1[2] + g1[3] + g1[4] + g1[5] + g1[6];
    float inv = fast_rcp(s1 * s1);
    int i = tid >> 6, j = tid & 63;
    float acc = 0.f;
    #pragma unroll
    for (int di = -3; di <= 3; ++di) {
        #pragma unroll
        for (int dj = -3; dj <= 3; ++dj) {
            int jj = j + dj;
            float val = (jj >= 0 && jj < 64) ? t2[i + 3 + di][jj] : 0.f;
            acc += g1[di + 3] * g1[dj + 3] * val;
        }
    }
    acc *= inv;
    float ov = acc - THRESH;
    float p = ov > 0.f ? ov * ov : 0.f;
    DPP5(p, op_add, 0.0f);
    float tot = rdlane(p, 31) + rdlane(p, 63);
    if ((tid & 63) == 0) atomicAdd(&pen[b], tot);
}

__global__ void finalize_kernel(const float* __restrict__ hpwl,
                                const float* __restrict__ pen,
                                float* __restrict__ out) {
    int i = threadIdx.x;
    if (i < B) out[i] = W_WL * hpwl[i] + W_CONG * pen[i];
}

} // namespace

extern "C" void kernel_launch(void* const* d_in, const int* in_sizes, int n_in,
                              void* d_out, int out_size, void* d_ws, size_t ws_size,
                              hipStream_t stream) {
    const float* positions    = (const float*)d_in[0];
    const int*   net_to_pin   = (const int*)d_in[1];
    const int*   pin_to_macro = (const int*)d_in[2];
    const float* pin_offsets  = (const float*)d_in[3];
    const float* rot_onehot   = (const float*)d_in[4];
    const float* net_weights  = (const float*)d_in[5];
    float* out = (float*)d_out;

    // ws: pin_pos | rudy | hpwl | pen | mac | fac | n2pT   (~28 MB)
    // slabs (512*16KB = 8.4 MB) ALIASES pin_pos (12.8 MB): pin_pos is dead
    // after bbox_kernel, and rudy_kernel runs strictly after it on the stream.
    float*  pin_pos = (float*)d_ws;
    float*  rudy    = pin_pos + (size_t)B * P * 2;
    float*  hpwl    = rudy + (size_t)B * 64 * 64;
    float*  pen     = hpwl + B;
    float4* mac     = (float4*)(pen + B);
    float4* fac     = mac + (size_t)B * V;             // B*NN*2 float4
    int*    n2pT    = (int*)(fac + (size_t)B * NN * 2);
    float*  slabs   = pin_pos;                 // reuse (see comment above)

    prep_kernel<<<(PREP_N + 255) / 256, 256, 0, stream>>>(
        positions, rot_onehot, mac, net_to_pin, n2pT, hpwl);
    pin_pos_kernel<<<(B * P / 2 + 255) / 256, 256, 0, stream>>>(
        mac, pin_to_macro, pin_offsets, pin_pos);
    bbox_kernel<<<A_GRID, 256, 0, stream>>>(pin_pos, n2pT, net_weights, fac, hpwl);
    rudy_kernel<<<NET_GRID, 256, 0, stream>>>(fac, slabs);
    rudy_reduce_kernel<<<64, 256, 0, stream>>>(slabs, rudy);
    conv_penalty_kernel<<<64, 256, 0, stream>>>(rudy, pen);
    finalize_kernel<<<1, 64, 0, stream>>>(hpwl, pen, out);
}